// Round 5
// baseline (87.335 us; speedup 1.0000x reference)
//
#include <hip/hip_runtime.h>

#define N   32
#define NN  1024
#define PS  34              // padded LDS stride (+2 border; aliasing is 2-way = free)
#define PSZ (PS * PS)       // 1156

// One WAVE (64 lanes) per batch element. Lane (ty,tx) owns a 4x4 cell tile in
// registers (interior of a 6x6 block g); border of g = halo re-read from LDS
// each sweep. LDS dist is padded 34x34 with an INF border so boundary handling
// is free. Per sweep: vectorized halo reads, FOUR in-register Gauss-Seidel
// rasters (all 4 diagonal quadrant directions: SE, NE, SW, NW) so information
// propagates fast along any path shape, paired write-backs, one
// __threadfence_block (compiler fence; single-wave DS is in-order so no
// s_barrier needed — R2 failed without the fence, R3/R4 pass with it).
//
// Ordering-freedom: every value ever assigned is an fp-fold of a source path,
// i.e. a valid upper bound; monotone-decreasing chaotic iteration from INF
// converges to the unique fixpoint = the reference's Dijkstra distances
// bitwise (validated absmax=0 in R1/R3/R4). So raster order and even stale
// register reuse inside a raster cannot corrupt the result. The termination
// certificate (a sweep with zero changes anywhere) is sound: if nothing
// changed, all values consulted equal current values, so the Bellman
// inequality was verified for all cells with fresh data.
__global__ __launch_bounds__(64, 1) void dijkstra_path_kernel(
    const float* __restrict__ weights, float* __restrict__ out)
{
    const int b    = blockIdx.x;
    const int lane = threadIdx.x & 63;
    const int ty   = lane >> 3;        // tile row 0..7
    const int tx   = lane & 7;         // tile col 0..7
    const int y0   = ty << 2;          // tile origin (global cell coords)
    const int x0   = tx << 2;

    __shared__ float dist[PSZ];        // P(y,x) = (y+1)*34 + (x+1)
    __shared__ int   pred[NN];
    __shared__ float pathf[NN];

    const float INF = __builtin_huge_valf();

    // ---- init LDS: dist = INF everywhere (incl. border), pathf = 0 ----
    #pragma unroll
    for (int k = 0; k < 19; ++k) {
        int idx = lane + k * 64;
        if (idx < PSZ) dist[idx] = INF;
    }
    #pragma unroll
    for (int k = 0; k < 16; ++k) pathf[lane + k * 64] = 0.0f;

    // ---- weights tile -> registers (float4 rows) ----
    float w[4][4];
    const float* wb = weights + b * NN;
    #pragma unroll
    for (int i = 0; i < 4; ++i) {
        const float4 v = *(const float4*)(wb + (y0 + i) * N + x0);
        w[i][0] = v.x; w[i][1] = v.y; w[i][2] = v.z; w[i][3] = v.w;
    }

    // ---- register state: 6x6 (interior = my 4x4 tile, border = halo) ----
    float g[6][6];
    #pragma unroll
    for (int i = 0; i < 6; ++i)
        #pragma unroll
        for (int j = 0; j < 6; ++j) g[i][j] = INF;
    if (lane == 0) {
        g[1][1] = 0.0f;
        dist[1 * PS + 1] = 0.0f;       // source visible to neighbors at sweep 1
    }
    __threadfence_block();             // publish init

    // one 8-neighbor relaxation of cell (i,j), i,j in 1..4
#define RELAX(i, j)                                                           \
    {                                                                         \
        const float m = fminf(                                                \
            fminf(fminf(g[(i)-1][(j)-1], g[(i)-1][(j)]),                      \
                  fminf(g[(i)-1][(j)+1], g[(i)][(j)-1])),                     \
            fminf(fminf(g[(i)][(j)+1], g[(i)+1][(j)-1]),                      \
                  fminf(g[(i)+1][(j)], g[(i)+1][(j)+1])));                    \
        const float nv = m + w[(i)-1][(j)-1];                                 \
        if (nv < g[(i)][(j)]) { g[(i)][(j)] = nv; changed = true; }           \
    }

    // ---- relaxation sweeps ----
    const int base_top = y0 * PS + x0;            // P(y0-1, x0-1); == 0 (mod 4)
    const int base_bot = (y0 + 5) * PS + x0;      // P(y0+4, x0-1); == 2 (mod 4)
    for (int it = 0; it < 256; ++it) {
        // top halo: aligned float4 + float2
        {
            const float4 a = *(const float4*)&dist[base_top];
            g[0][0] = a.x; g[0][1] = a.y; g[0][2] = a.z; g[0][3] = a.w;
            const float2 c = *(const float2*)&dist[base_top + 4];
            g[0][4] = c.x; g[0][5] = c.y;
        }
        // bottom halo: two aligned float4 straddling base_bot; keep cols x0-1..x0+4
        {
            const float4 a = *(const float4*)&dist[base_bot - 2];
            const float4 c = *(const float4*)&dist[base_bot + 2];
            g[5][0] = a.z; g[5][1] = a.w;
            g[5][2] = c.x; g[5][3] = c.y; g[5][4] = c.z; g[5][5] = c.w;
        }
        // side halos: per-row pairs (offset 0 and 5) -> ds_read2_b32
        #pragma unroll
        for (int i = 0; i < 4; ++i) {
            const int r = (y0 + i + 1) * PS + x0;
            g[1 + i][0] = dist[r];
            g[1 + i][5] = dist[r + 5];
        }

        bool changed = false;
        // raster SE: i asc, j asc
        #pragma unroll
        for (int i = 1; i <= 4; ++i)
            #pragma unroll
            for (int j = 1; j <= 4; ++j) RELAX(i, j)
        // raster NE: i desc, j asc
        #pragma unroll
        for (int i = 4; i >= 1; --i)
            #pragma unroll
            for (int j = 1; j <= 4; ++j) RELAX(i, j)
        // raster SW: i asc, j desc
        #pragma unroll
        for (int i = 1; i <= 4; ++i)
            #pragma unroll
            for (int j = 4; j >= 1; --j) RELAX(i, j)
        // raster NW: i desc, j desc
        #pragma unroll
        for (int i = 4; i >= 1; --i)
            #pragma unroll
            for (int j = 4; j >= 1; --j) RELAX(i, j)

        // write-back; adjacent scalar stores fuse to ds_write2_b32
        #pragma unroll
        for (int i = 0; i < 4; ++i) {
            const int r = (y0 + i + 1) * PS + (x0 + 1);
            dist[r]     = g[1 + i][1];
            dist[r + 1] = g[1 + i][2];
            dist[r + 2] = g[1 + i][3];
            dist[r + 3] = g[1 + i][4];
        }
        __threadfence_block();         // publish writes, force halo reload
        if (!__any((int)changed)) break;
    }
#undef RELAX

    // ---- predecessors: argmin over 8 neighbors of fp(dist_u + w_v), DIRS order ----
    // (g border = final halo: the terminating sweep saw no changes anywhere)
    const int dy[8] = {-1, 1, 0, 0, -1, -1, 1, 1};
    const int dx[8] = { 0, 0,-1, 1, -1,  1,-1, 1};
    #pragma unroll
    for (int i = 0; i < 4; ++i)
        #pragma unroll
        for (int j = 0; j < 4; ++j) {
            const int yy = y0 + i, xx = x0 + j;
            const int t  = yy * N + xx;
            int p = 0;
            if (t != 0) {
                float best = INF;
                #pragma unroll
                for (int k = 0; k < 8; ++k) {
                    const float u = g[1 + i + dy[k]][1 + j + dx[k]];  // OOB -> INF border
                    const float c = u + w[i][j];
                    if (c < best) { best = c; p = (yy + dy[k]) * N + (xx + dx[k]); }
                }
            }
            pred[t] = p;
        }
    __threadfence_block();             // pred visible to lane 0

    // ---- serial backtrack from (31,31); pred[0]==0 is the fixed point ----
    if (lane == 0) {
        int cur = NN - 1;
        pathf[cur] = 1.0f;
        for (int s = 0; s < NN && cur != 0; ++s) {
            cur = pred[cur];
            pathf[cur] = 1.0f;
        }
    }
    __threadfence_block();             // lane 0's path writes visible to all

    // ---- write output (float4 rows) ----
    float* ob = out + b * NN;
    #pragma unroll
    for (int i = 0; i < 4; ++i) {
        const int t = (y0 + i) * N + x0;
        const float4 v = *(const float4*)&pathf[t];
        *(float4*)(ob + t) = v;
    }
}

extern "C" void kernel_launch(void* const* d_in, const int* in_sizes, int n_in,
                              void* d_out, int out_size, void* d_ws, size_t ws_size,
                              hipStream_t stream) {
    const float* w = (const float*)d_in[0];
    float* out = (float*)d_out;
    const int b = in_sizes[0] / NN;   // 128
    dijkstra_path_kernel<<<dim3(b), dim3(64), 0, stream>>>(w, out);
}

// Round 6
// 74.576 us; speedup vs baseline: 1.1711x; 1.1711x over previous
//
#include <hip/hip_runtime.h>

#define N   32
#define NN  1024

// One WAVE (64 lanes) per batch element. Lane (ty,tx) owns a 4x4 cell tile in
// registers (interior of a 6x6 block g). The halo (border of g) is fetched
// each sweep from the 8 neighboring lanes' REGISTERS via __shfl (ds_bpermute:
// in-register crossbar — no LDS array, no fence, no write->read round-trip,
// no bank conflicts). Edge lanes mask their missing halo to INF via cndmask.
// Per sweep: 20 shuffles + 2 in-register Gauss-Seidel rasters (SE, NW).
// Convergence via wave-level __any. LDS is used only for pred/path in the
// epilogue (single-wave in-order DS + __threadfence_block compiler fence —
// the pattern validated in R3/R4/R5; R2 showed the fence is mandatory).
//
// Ordering-freedom / exactness: every assigned value is an fp-fold
// (((0+w)+w)+...) of some source path, i.e. a valid upper bound; the
// monotone-decreasing chaotic iteration from INF converges to the unique
// fixpoint = min-over-paths fold = the reference's Dijkstra distances
// bitwise (validated absmax=0 in R1/R3/R4/R5 under four different orders).
// Termination certificate: a sweep with fresh halos and zero changes
// verifies the Bellman inequality everywhere.
__global__ __launch_bounds__(64, 1) void dijkstra_path_kernel(
    const float* __restrict__ weights, float* __restrict__ out)
{
    const int b    = blockIdx.x;
    const int lane = threadIdx.x & 63;
    const int ty   = lane >> 3;        // tile row 0..7
    const int tx   = lane & 7;         // tile col 0..7
    const int y0   = ty << 2;          // tile origin (global cell coords)
    const int x0   = tx << 2;

    __shared__ int   pred[NN];         // 4 KB
    __shared__ float pathf[NN];        // 4 KB

    const float INF = __builtin_huge_valf();

    // ---- pathf = 0 ----
    #pragma unroll
    for (int k = 0; k < 16; ++k) pathf[lane + k * 64] = 0.0f;

    // ---- weights tile -> registers (float4 rows) ----
    float w[4][4];
    const float* wb = weights + b * NN;
    #pragma unroll
    for (int i = 0; i < 4; ++i) {
        const float4 v = *(const float4*)(wb + (y0 + i) * N + x0);
        w[i][0] = v.x; w[i][1] = v.y; w[i][2] = v.z; w[i][3] = v.w;
    }

    // ---- register state: 6x6 (interior = my 4x4 tile, border = halo) ----
    float g[6][6];
    #pragma unroll
    for (int i = 0; i < 6; ++i)
        #pragma unroll
        for (int j = 0; j < 6; ++j) g[i][j] = INF;
    if (lane == 0) g[1][1] = 0.0f;     // source (0,0)

    const bool hT = (ty > 0), hB = (ty < 7), hL = (tx > 0), hR = (tx < 7);

    // one 8-neighbor relaxation of cell (i,j), i,j in 1..4 (min3-friendly tree)
#define RELAX(i, j)                                                           \
    {                                                                         \
        const float m = fminf(                                                \
            fminf(fminf(g[(i)-1][(j)-1], g[(i)-1][(j)]),                      \
                  fminf(g[(i)-1][(j)+1], g[(i)][(j)-1])),                     \
            fminf(fminf(g[(i)][(j)+1], g[(i)+1][(j)-1]),                      \
                  fminf(g[(i)+1][(j)], g[(i)+1][(j)+1])));                    \
        const float nv = m + w[(i)-1][(j)-1];                                 \
        if (nv < g[(i)][(j)]) { g[(i)][(j)] = nv; changed = true; }           \
    }

    // ---- relaxation sweeps (register-only halo exchange) ----
    for (int it = 0; it < 256; ++it) {
        // All shuffles first: payloads are pre-sweep values (Jacobi across
        // tiles, GS within tile). Out-of-range srcLane wraps; masked below.
        float tT[4], tB[4], tL[4], tR[4];
        #pragma unroll
        for (int j = 0; j < 4; ++j) tT[j] = __shfl(g[4][1 + j], lane - 8);
        #pragma unroll
        for (int j = 0; j < 4; ++j) tB[j] = __shfl(g[1][1 + j], lane + 8);
        #pragma unroll
        for (int i = 0; i < 4; ++i) tL[i] = __shfl(g[1 + i][4], lane - 1);
        #pragma unroll
        for (int i = 0; i < 4; ++i) tR[i] = __shfl(g[1 + i][1], lane + 1);
        const float cTL = __shfl(g[4][4], lane - 9);
        const float cTR = __shfl(g[4][1], lane - 7);
        const float cBL = __shfl(g[1][4], lane + 7);
        const float cBR = __shfl(g[1][1], lane + 9);

        #pragma unroll
        for (int j = 0; j < 4; ++j) {
            g[0][1 + j] = hT ? tT[j] : INF;
            g[5][1 + j] = hB ? tB[j] : INF;
        }
        #pragma unroll
        for (int i = 0; i < 4; ++i) {
            g[1 + i][0] = hL ? tL[i] : INF;
            g[1 + i][5] = hR ? tR[i] : INF;
        }
        g[0][0] = (hT && hL) ? cTL : INF;
        g[0][5] = (hT && hR) ? cTR : INF;
        g[5][0] = (hB && hL) ? cBL : INF;
        g[5][5] = (hB && hR) ? cBR : INF;

        bool changed = false;
        // raster SE: i asc, j asc
        #pragma unroll
        for (int i = 1; i <= 4; ++i)
            #pragma unroll
            for (int j = 1; j <= 4; ++j) RELAX(i, j)
        // raster NW: i desc, j desc
        #pragma unroll
        for (int i = 4; i >= 1; --i)
            #pragma unroll
            for (int j = 4; j >= 1; --j) RELAX(i, j)

        if (!__any((int)changed)) break;
    }
#undef RELAX

    // ---- predecessors: argmin over 8 neighbors of fp(dist_u + w_v), DIRS order ----
    // (g border = final halo: the terminating sweep had fresh halos, no changes)
    const int dy[8] = {-1, 1, 0, 0, -1, -1, 1, 1};
    const int dx[8] = { 0, 0,-1, 1, -1,  1,-1, 1};
    #pragma unroll
    for (int i = 0; i < 4; ++i)
        #pragma unroll
        for (int j = 0; j < 4; ++j) {
            const int yy = y0 + i, xx = x0 + j;
            const int t  = yy * N + xx;
            int p = 0;
            if (t != 0) {
                float best = INF;
                #pragma unroll
                for (int k = 0; k < 8; ++k) {
                    const float u = g[1 + i + dy[k]][1 + j + dx[k]];  // OOB -> INF border
                    const float c = u + w[i][j];
                    if (c < best) { best = c; p = (yy + dy[k]) * N + (xx + dx[k]); }
                }
            }
            pred[t] = p;
        }
    __threadfence_block();             // publish pred (compiler fence; wave DS in-order)

    // ---- serial backtrack from (31,31); pred[0]==0 is the fixed point ----
    if (lane == 0) {
        int cur = NN - 1;
        pathf[cur] = 1.0f;
        for (int s = 0; s < NN && cur != 0; ++s) {
            cur = pred[cur];
            pathf[cur] = 1.0f;
        }
    }
    __threadfence_block();             // publish lane 0's path writes

    // ---- write output (float4 rows) ----
    float* ob = out + b * NN;
    #pragma unroll
    for (int i = 0; i < 4; ++i) {
        const int t = (y0 + i) * N + x0;
        const float4 v = *(const float4*)&pathf[t];
        *(float4*)(ob + t) = v;
    }
}

extern "C" void kernel_launch(void* const* d_in, const int* in_sizes, int n_in,
                              void* d_out, int out_size, void* d_ws, size_t ws_size,
                              hipStream_t stream) {
    const float* w = (const float*)d_in[0];
    float* out = (float*)d_out;
    const int b = in_sizes[0] / NN;   // 128
    dijkstra_path_kernel<<<dim3(b), dim3(64), 0, stream>>>(w, out);
}

// Round 7
// 72.494 us; speedup vs baseline: 1.2047x; 1.0287x over previous
//
#include <hip/hip_runtime.h>

#define N   32
#define NN  1024

// One WAVE (64 lanes) per batch element. Lane (ty,tx) owns a 4x4 cell tile in
// registers (interior of a 6x6 block g). Halo = border of g, fetched from the
// 8 neighboring lanes' registers via __shfl (ds_bpermute crossbar; no LDS, no
// fence, no bank conflicts). Edge lanes mask their missing halo to INF.
//
// Per sweep: TWO halo exchanges + TWO min3-fused Gauss-Seidel rasters
// (exchange -> SE raster -> exchange -> NW raster -> convergence check).
// Exchanging before EACH raster means the NW raster sees post-SE neighbor
// values (lanes are lockstep), improving cross-tile freshness per sweep.
//
// Termination: check the NW raster's 'changed' only. Sound because the
// pre-NW exchange delivered the neighbors' CURRENT values; a zero-change NW
// raster relaxed every cell against fresh data, verifying the Bellman
// inequality everywhere -> fixpoint reached.
//
// Exactness: every assigned value is an fp-fold (((0+w)+w)+...) of a source
// path; monotone-decreasing chaotic iteration from INF converges to the
// unique fixpoint = min-over-paths fold = the reference's Dijkstra distances
// bitwise (validated absmax=0 in R1/R3/R4/R5/R6 under five orders).
// LDS only in the epilogue (pred/path) with the R3-validated
// single-wave __threadfence_block pattern (R2 showed the fence is mandatory).
__global__ __launch_bounds__(64, 1) void dijkstra_path_kernel(
    const float* __restrict__ weights, float* __restrict__ out)
{
    const int b    = blockIdx.x;
    const int lane = threadIdx.x & 63;
    const int ty   = lane >> 3;        // tile row 0..7
    const int tx   = lane & 7;         // tile col 0..7
    const int y0   = ty << 2;          // tile origin (global cell coords)
    const int x0   = tx << 2;

    __shared__ int   pred[NN];         // 4 KB
    __shared__ float pathf[NN];        // 4 KB

    const float INF = __builtin_huge_valf();

    // ---- pathf = 0 ----
    #pragma unroll
    for (int k = 0; k < 16; ++k) pathf[lane + k * 64] = 0.0f;

    // ---- weights tile -> registers (float4 rows) ----
    float w[4][4];
    const float* wb = weights + b * NN;
    #pragma unroll
    for (int i = 0; i < 4; ++i) {
        const float4 v = *(const float4*)(wb + (y0 + i) * N + x0);
        w[i][0] = v.x; w[i][1] = v.y; w[i][2] = v.z; w[i][3] = v.w;
    }

    // ---- register state: 6x6 (interior = my 4x4 tile, border = halo) ----
    float g[6][6];
    #pragma unroll
    for (int i = 0; i < 6; ++i)
        #pragma unroll
        for (int j = 0; j < 6; ++j) g[i][j] = INF;
    if (lane == 0) g[1][1] = 0.0f;     // source (0,0)

    const bool hT = (ty > 0), hB = (ty < 7), hL = (tx > 0), hR = (tx < 7);

    // fetch halo from neighbor lanes' registers; mask off-grid edges to INF
#define EXCHANGE()                                                            \
    {                                                                         \
        float tT[4], tB[4], tL[4], tR[4];                                     \
        _Pragma("unroll")                                                     \
        for (int j = 0; j < 4; ++j) tT[j] = __shfl(g[4][1 + j], lane - 8);    \
        _Pragma("unroll")                                                     \
        for (int j = 0; j < 4; ++j) tB[j] = __shfl(g[1][1 + j], lane + 8);    \
        _Pragma("unroll")                                                     \
        for (int i = 0; i < 4; ++i) tL[i] = __shfl(g[1 + i][4], lane - 1);    \
        _Pragma("unroll")                                                     \
        for (int i = 0; i < 4; ++i) tR[i] = __shfl(g[1 + i][1], lane + 1);    \
        const float cTL = __shfl(g[4][4], lane - 9);                          \
        const float cTR = __shfl(g[4][1], lane - 7);                          \
        const float cBL = __shfl(g[1][4], lane + 7);                          \
        const float cBR = __shfl(g[1][1], lane + 9);                          \
        _Pragma("unroll")                                                     \
        for (int j = 0; j < 4; ++j) {                                         \
            g[0][1 + j] = hT ? tT[j] : INF;                                   \
            g[5][1 + j] = hB ? tB[j] : INF;                                   \
        }                                                                     \
        _Pragma("unroll")                                                     \
        for (int i = 0; i < 4; ++i) {                                         \
            g[1 + i][0] = hL ? tL[i] : INF;                                   \
            g[1 + i][5] = hR ? tR[i] : INF;                                   \
        }                                                                     \
        g[0][0] = (hT && hL) ? cTL : INF;                                     \
        g[0][5] = (hT && hR) ? cTR : INF;                                     \
        g[5][0] = (hB && hL) ? cBL : INF;                                     \
        g[5][5] = (hB && hR) ? cBR : INF;                                     \
    }

    // min3-fused 8-neighbor relax: v_min3 x3 + v_min + v_add + v_cmp + v_min
    // (changed-accumulation goes to the scalar pipe, co-issued with VALU)
#define RELAX(i, j)                                                           \
    {                                                                         \
        const float old = g[(i)][(j)];                                        \
        const float a = fminf(fminf(g[(i)-1][(j)-1], g[(i)-1][(j)]),          \
                              g[(i)-1][(j)+1]);                               \
        const float c = fminf(fminf(g[(i)][(j)-1], g[(i)][(j)+1]),            \
                              g[(i)+1][(j)-1]);                               \
        const float e = fminf(g[(i)+1][(j)], g[(i)+1][(j)+1]);                \
        const float m = fminf(fminf(a, c), e);                                \
        const float nv = m + w[(i)-1][(j)-1];                                 \
        changed |= (nv < old);                                                \
        g[(i)][(j)] = fminf(old, nv);                                         \
    }

    // ---- relaxation sweeps ----
    for (int it = 0; it < 384; ++it) {
        bool changed = false;
        EXCHANGE()
        // raster SE: i asc, j asc
        #pragma unroll
        for (int i = 1; i <= 4; ++i)
            #pragma unroll
            for (int j = 1; j <= 4; ++j) RELAX(i, j)
        changed = false;               // only the NW raster's result certifies
        EXCHANGE()
        // raster NW: i desc, j desc — runs on post-SE neighbor values
        #pragma unroll
        for (int i = 4; i >= 1; --i)
            #pragma unroll
            for (int j = 4; j >= 1; --j) RELAX(i, j)
        if (!__any((int)changed)) break;
    }
#undef RELAX
#undef EXCHANGE

    // ---- predecessors: argmin over 8 neighbors of fp(dist_u + w_v), DIRS order ----
    // (halo in g is fresh: fetched before the zero-change NW raster)
    const int dy[8] = {-1, 1, 0, 0, -1, -1, 1, 1};
    const int dx[8] = { 0, 0,-1, 1, -1,  1,-1, 1};
    #pragma unroll
    for (int i = 0; i < 4; ++i)
        #pragma unroll
        for (int j = 0; j < 4; ++j) {
            const int yy = y0 + i, xx = x0 + j;
            const int t  = yy * N + xx;
            int p = 0;
            if (t != 0) {
                float best = INF;
                #pragma unroll
                for (int k = 0; k < 8; ++k) {
                    const float u = g[1 + i + dy[k]][1 + j + dx[k]];  // OOB -> INF
                    const float c = u + w[i][j];
                    if (c < best) { best = c; p = (yy + dy[k]) * N + (xx + dx[k]); }
                }
            }
            pred[t] = p;
        }
    __threadfence_block();             // publish pred (compiler fence; wave DS in-order)

    // ---- serial backtrack from (31,31); pred[0]==0 is the fixed point ----
    if (lane == 0) {
        int cur = NN - 1;
        pathf[cur] = 1.0f;
        for (int s = 0; s < NN && cur != 0; ++s) {
            cur = pred[cur];
            pathf[cur] = 1.0f;
        }
    }
    __threadfence_block();             // publish lane 0's path writes

    // ---- write output (float4 rows) ----
    float* ob = out + b * NN;
    #pragma unroll
    for (int i = 0; i < 4; ++i) {
        const int t = (y0 + i) * N + x0;
        const float4 v = *(const float4*)&pathf[t];
        *(float4*)(ob + t) = v;
    }
}

extern "C" void kernel_launch(void* const* d_in, const int* in_sizes, int n_in,
                              void* d_out, int out_size, void* d_ws, size_t ws_size,
                              hipStream_t stream) {
    const float* w = (const float*)d_in[0];
    float* out = (float*)d_out;
    const int b = in_sizes[0] / NN;   // 128
    dijkstra_path_kernel<<<dim3(b), dim3(64), 0, stream>>>(w, out);
}